// Round 3
// baseline (343.245 us; speedup 1.0000x reference)
//
#include <hip/hip_runtime.h>

#define NCLS   18
#define TROWS  128                      // rows per wave-tile
#define TWORDS (TROWS * NCLS)           // 2304 floats = 9216 B per array per tile
#define NV4    9                        // float4 wave-loads per array per tile (9*64*16B = 9216)

// ---- per-tile body: stage regs->LDS, prefetch next into same regs, compute ----
// Wave-private (no __syncthreads): compiler inserts counted vmcnt/lgkmcnt only.
__device__ __forceinline__ void tile_body(
    float4* __restrict__ bufX, float4* __restrict__ bufL, int lane,
    float4 (&xr)[NV4], float4 (&lr)[NV4],
    const float* __restrict__ logits, const float* __restrict__ labels,
    int tn, int nTiles, float& acc)
{
    // stage current tile (waits counted-vmcnt for xr/lr only)
    #pragma unroll
    for (int j = 0; j < NV4; ++j) bufX[j * 64 + lane] = xr[j];
    #pragma unroll
    for (int j = 0; j < NV4; ++j) bufL[j * 64 + lane] = lr[j];

    // refill regs with tile tn (2 tiles ahead) -> stays in flight under compute
    if (tn < nTiles) {
        const float4* gx = (const float4*)(logits + (size_t)tn * TWORDS);
        const float4* gl = (const float4*)(labels + (size_t)tn * TWORDS);
        #pragma unroll
        for (int j = 0; j < NV4; ++j) xr[j] = gx[j * 64 + lane];
        #pragma unroll
        for (int j = 0; j < NV4; ++j) lr[j] = gl[j * 64 + lane];
    }

    // transpose read: lane owns rows 2*lane, 2*lane+1 (144 B = 9 float4, 16B-aligned)
    float x[2 * NCLS];
    #pragma unroll
    for (int j = 0; j < NV4; ++j) {
        float4 v = bufX[lane * 9 + j];
        x[4 * j + 0] = v.x; x[4 * j + 1] = v.y;
        x[4 * j + 2] = v.z; x[4 * j + 3] = v.w;
    }
    float mA = x[0], mB = x[18];
    #pragma unroll
    for (int c = 1; c < NCLS; ++c) { mA = fmaxf(mA, x[c]); mB = fmaxf(mB, x[NCLS + c]); }
    float seA = 0.f, seB = 0.f;
    #pragma unroll
    for (int c = 0; c < NCLS; ++c) {
        seA += __expf(x[c] - mA);
        seB += __expf(x[NCLS + c] - mB);
    }
    float lseA = mA + __logf(seA);
    float lseB = mB + __logf(seB);

    // labels pass: acc += sum_e lb_e * (lse_row(e) - x_e); row split is compile-time
    #pragma unroll
    for (int j = 0; j < NV4; ++j) {
        float4 w = bufL[lane * 9 + j];
        float s0 = (4 * j + 0 < NCLS) ? lseA : lseB;
        float s1 = (4 * j + 1 < NCLS) ? lseA : lseB;
        float s2 = (4 * j + 2 < NCLS) ? lseA : lseB;
        float s3 = (4 * j + 3 < NCLS) ? lseA : lseB;
        acc = fmaf(w.x, s0 - x[4 * j + 0], acc);
        acc = fmaf(w.y, s1 - x[4 * j + 1], acc);
        acc = fmaf(w.z, s2 - x[4 * j + 2], acc);
        acc = fmaf(w.w, s3 - x[4 * j + 3], acc);
    }
}

__global__ __launch_bounds__(256, 2) void ce_soft_main(
    const float* __restrict__ logits,
    const float* __restrict__ labels,
    float* __restrict__ partial,
    int B)
{
    // wave-private LDS slices: 4 waves x (9216 X + 9216 L) = 73728 B -> 2 blocks/CU
    __shared__ float sX[4][TWORDS];
    __shared__ float sL[4][TWORDS];
    __shared__ float sWS[4];

    const int tid  = threadIdx.x;
    const int lane = tid & 63;
    const int wid  = tid >> 6;
    float4* bufX = (float4*)sX[wid];
    float4* bufL = (float4*)sL[wid];

    const int nTiles  = B / TROWS;
    const int wgid    = blockIdx.x * 4 + wid;
    const int wstride = gridDim.x * 4;

    float acc = 0.f;
    float4 xA[NV4], lA[NV4], xB[NV4], lB[NV4];

    // prologue: 2-deep register prefetch (tiles wgid, wgid+wstride)
    {
        int tA = wgid, tB = wgid + wstride;
        if (tA < nTiles) {
            const float4* gx = (const float4*)(logits + (size_t)tA * TWORDS);
            const float4* gl = (const float4*)(labels + (size_t)tA * TWORDS);
            #pragma unroll
            for (int j = 0; j < NV4; ++j) xA[j] = gx[j * 64 + lane];
            #pragma unroll
            for (int j = 0; j < NV4; ++j) lA[j] = gl[j * 64 + lane];
        }
        if (tB < nTiles) {
            const float4* gx = (const float4*)(logits + (size_t)tB * TWORDS);
            const float4* gl = (const float4*)(labels + (size_t)tB * TWORDS);
            #pragma unroll
            for (int j = 0; j < NV4; ++j) xB[j] = gx[j * 64 + lane];
            #pragma unroll
            for (int j = 0; j < NV4; ++j) lB[j] = gl[j * 64 + lane];
        }
    }

    // main loop: 2 tiles per iteration, static A/B register sets, NO barriers
    for (int t = wgid; t < nTiles; t += 2 * wstride) {
        tile_body(bufX, bufL, lane, xA, lA, logits, labels,
                  t + 2 * wstride, nTiles, acc);
        int t1 = t + wstride;
        if (t1 < nTiles)
            tile_body(bufX, bufL, lane, xB, lB, logits, labels,
                      t1 + 2 * wstride, nTiles, acc);
    }

    // generic tail (B % TROWS != 0) — empty for B = 2,000,000
    for (int row = nTiles * TROWS + blockIdx.x * blockDim.x + tid; row < B;
         row += gridDim.x * blockDim.x) {
        const float2* o2 = (const float2*)(logits + (size_t)row * NCLS);
        const float2* l2 = (const float2*)(labels + (size_t)row * NCLS);
        float x[NCLS], l[NCLS];
        #pragma unroll
        for (int k = 0; k < NCLS / 2; ++k) {
            float2 v = o2[k]; x[2 * k] = v.x; x[2 * k + 1] = v.y;
            float2 w = l2[k]; l[2 * k] = w.x; l[2 * k + 1] = w.y;
        }
        float mm = x[0];
        #pragma unroll
        for (int c = 1; c < NCLS; ++c) mm = fmaxf(mm, x[c]);
        float se = 0.f, dot = 0.f, sl = 0.f;
        #pragma unroll
        for (int c = 0; c < NCLS; ++c) {
            se += __expf(x[c] - mm);
            dot = fmaf(l[c], x[c], dot);
            sl += l[c];
        }
        acc = fmaf(sl, mm + __logf(se), acc - dot);
    }

    // block reduction -> plain store of partial (no atomic, no memset)
    #pragma unroll
    for (int off = 32; off > 0; off >>= 1)
        acc += __shfl_down(acc, off, 64);
    if (lane == 0) sWS[wid] = acc;
    __syncthreads();
    if (tid == 0)
        partial[blockIdx.x] = sWS[0] + sWS[1] + sWS[2] + sWS[3];
}

__global__ __launch_bounds__(256) void ce_soft_finish(
    const float* __restrict__ partial, float* __restrict__ result,
    int n, float invB)
{
    float s = 0.f;
    for (int i = threadIdx.x; i < n; i += 256) s += partial[i];
    #pragma unroll
    for (int off = 32; off > 0; off >>= 1)
        s += __shfl_down(s, off, 64);
    __shared__ float ws[4];
    int lane = threadIdx.x & 63, wid = threadIdx.x >> 6;
    if (lane == 0) ws[wid] = s;
    __syncthreads();
    if (threadIdx.x == 0)
        result[0] = (ws[0] + ws[1] + ws[2] + ws[3]) * invB;  // plain store overwrites poison
}

extern "C" void kernel_launch(void* const* d_in, const int* in_sizes, int n_in,
                              void* d_out, int out_size, void* d_ws, size_t ws_size,
                              hipStream_t stream) {
    const float* logits = (const float*)d_in[0];
    const float* labels = (const float*)d_in[1];
    float* result = (float*)d_out;

    int B = in_sizes[0] / NCLS;            // 2,000,000

    // grid = 512: 2 blocks/CU (LDS/VGPR-capped) x 256 CU = exactly resident
    int grid = 512;
    if (ws_size < (size_t)grid * sizeof(float)) {
        grid = (int)(ws_size / sizeof(float));
        if (grid > 512) grid = 512;
        if (grid < 1) grid = 1;
    }
    float* partial = (float*)d_ws;

    ce_soft_main<<<grid, 256, 0, stream>>>(logits, labels, partial, B);
    ce_soft_finish<<<1, 256, 0, stream>>>(partial, result, grid, 1.0f / (float)B);
}

// Round 5
// 295.924 us; speedup vs baseline: 1.1599x; 1.1599x over previous
//
#include <hip/hip_runtime.h>

#define NCLS   18
#define TROWS  128                      // rows per wave-tile
#define TWORDS (TROWS * NCLS)           // 2304 floats = 9216 B per array per tile
#define NF4    (TWORDS / 4)             // 576 float4 per array per tile

// 9-fold repetition helper (9 coalesced float4 wave-loads per array per tile)
#define REP9(F) F(0) F(1) F(2) F(3) F(4) F(5) F(6) F(7) F(8)

__global__ __launch_bounds__(256) void ce_soft_main(
    const float* __restrict__ logits,
    const float* __restrict__ labels,
    float* __restrict__ partial,
    int B)
{
    // wave-private LDS slices: 4 waves x (9216 X + 9216 L) = 73728 B -> 2 blocks/CU
    __shared__ float4 sX[4][NF4];
    __shared__ float4 sL[4][NF4];
    __shared__ float sWS[4];

    const int tid  = threadIdx.x;
    const int lane = tid & 63;
    const int wid  = tid >> 6;
    float4* bufX = &sX[wid][0];
    float4* bufL = &sL[wid][0];

    const int nTiles  = B / TROWS;             // 15625 for B = 2,000,000 (exact)
    const int wgid    = blockIdx.x * 4 + wid;  // global wave id
    const int wstride = gridDim.x * 4;

    float acc = 0.0f;

    // ---- prefetch registers: 18 individually-named float4 (nothing address-takeable) ----
#define DECLP(i) float4 px##i, pl##i;
    REP9(DECLP)
#undef DECLP

    if (wgid < nTiles) {
        const float4* gx = (const float4*)(logits + (size_t)wgid * TWORDS) + lane;
        const float4* gl = (const float4*)(labels + (size_t)wgid * TWORDS) + lane;
#define LOADP(i) px##i = gx[64 * i]; pl##i = gl[64 * i];
        REP9(LOADP)
#undef LOADP
    }

    // ---- main loop: zero __syncthreads; per-wave counted vmcnt/lgkmcnt only ----
    for (int t = wgid; t < nTiles; t += wstride) {
        // stage current tile regs -> wave-private LDS (coalesced linear layout)
#define STX(i) bufX[64 * i + lane] = px##i;
        REP9(STX)
#undef STX
#define STL(i) bufL[64 * i + lane] = pl##i;
        REP9(STL)
#undef STL

        // refill prefetch regs with the NEXT tile -> in flight under this compute
        int tn = t + wstride;
        if (tn < nTiles) {
            const float4* gx = (const float4*)(logits + (size_t)tn * TWORDS) + lane;
            const float4* gl = (const float4*)(labels + (size_t)tn * TWORDS) + lane;
#define LOADP(i) px##i = gx[64 * i]; pl##i = gl[64 * i];
            REP9(LOADP)
#undef LOADP
        }

        // transpose read: lane owns rows 2*lane (words 0..17) and 2*lane+1 (18..35).
        // DS pipe processes a wave's LDS ops in program order -> the ds_reads of
        // this tile complete against this tile's ds_writes without a barrier.
        const float4* rx = bufX + lane * 9;    // 144 B per lane, 16B-aligned
#define RDX(i) float4 v##i = rx[i];
        REP9(RDX)
#undef RDX

        float mA = fmaxf(fmaxf(fmaxf(v0.x, v0.y), fmaxf(v0.z, v0.w)),
                   fmaxf(fmaxf(fmaxf(v1.x, v1.y), fmaxf(v1.z, v1.w)),
                   fmaxf(fmaxf(fmaxf(v2.x, v2.y), fmaxf(v2.z, v2.w)),
                   fmaxf(fmaxf(fmaxf(v3.x, v3.y), fmaxf(v3.z, v3.w)),
                         fmaxf(v4.x, v4.y)))));
        float mB = fmaxf(fmaxf(fmaxf(v5.x, v5.y), fmaxf(v5.z, v5.w)),
                   fmaxf(fmaxf(fmaxf(v6.x, v6.y), fmaxf(v6.z, v6.w)),
                   fmaxf(fmaxf(fmaxf(v7.x, v7.y), fmaxf(v7.z, v7.w)),
                   fmaxf(fmaxf(fmaxf(v8.x, v8.y), fmaxf(v8.z, v8.w)),
                         fmaxf(v4.z, v4.w)))));

        float seA = __expf(v0.x - mA) + __expf(v0.y - mA) + __expf(v0.z - mA) + __expf(v0.w - mA)
                  + __expf(v1.x - mA) + __expf(v1.y - mA) + __expf(v1.z - mA) + __expf(v1.w - mA)
                  + __expf(v2.x - mA) + __expf(v2.y - mA) + __expf(v2.z - mA) + __expf(v2.w - mA)
                  + __expf(v3.x - mA) + __expf(v3.y - mA) + __expf(v3.z - mA) + __expf(v3.w - mA)
                  + __expf(v4.x - mA) + __expf(v4.y - mA);
        float seB = __expf(v4.z - mB) + __expf(v4.w - mB)
                  + __expf(v5.x - mB) + __expf(v5.y - mB) + __expf(v5.z - mB) + __expf(v5.w - mB)
                  + __expf(v6.x - mB) + __expf(v6.y - mB) + __expf(v6.z - mB) + __expf(v6.w - mB)
                  + __expf(v7.x - mB) + __expf(v7.y - mB) + __expf(v7.z - mB) + __expf(v7.w - mB)
                  + __expf(v8.x - mB) + __expf(v8.y - mB) + __expf(v8.z - mB) + __expf(v8.w - mB);

        float lseA = mA + __logf(seA);
        float lseB = mB + __logf(seB);

        // labels pass: acc += sum_e l_e * (lse_row(e) - x_e); row split compile-time
        const float4* rl = bufL + lane * 9;
        {
            float4 w;
            w = rl[0];
            acc = fmaf(w.x, lseA - v0.x, acc); acc = fmaf(w.y, lseA - v0.y, acc);
            acc = fmaf(w.z, lseA - v0.z, acc); acc = fmaf(w.w, lseA - v0.w, acc);
            w = rl[1];
            acc = fmaf(w.x, lseA - v1.x, acc); acc = fmaf(w.y, lseA - v1.y, acc);
            acc = fmaf(w.z, lseA - v1.z, acc); acc = fmaf(w.w, lseA - v1.w, acc);
            w = rl[2];
            acc = fmaf(w.x, lseA - v2.x, acc); acc = fmaf(w.y, lseA - v2.y, acc);
            acc = fmaf(w.z, lseA - v2.z, acc); acc = fmaf(w.w, lseA - v2.w, acc);
            w = rl[3];
            acc = fmaf(w.x, lseA - v3.x, acc); acc = fmaf(w.y, lseA - v3.y, acc);
            acc = fmaf(w.z, lseA - v3.z, acc); acc = fmaf(w.w, lseA - v3.w, acc);
            w = rl[4];
            acc = fmaf(w.x, lseA - v4.x, acc); acc = fmaf(w.y, lseA - v4.y, acc);
            acc = fmaf(w.z, lseB - v4.z, acc); acc = fmaf(w.w, lseB - v4.w, acc);
            w = rl[5];
            acc = fmaf(w.x, lseB - v5.x, acc); acc = fmaf(w.y, lseB - v5.y, acc);
            acc = fmaf(w.z, lseB - v5.z, acc); acc = fmaf(w.w, lseB - v5.w, acc);
            w = rl[6];
            acc = fmaf(w.x, lseB - v6.x, acc); acc = fmaf(w.y, lseB - v6.y, acc);
            acc = fmaf(w.z, lseB - v6.z, acc); acc = fmaf(w.w, lseB - v6.w, acc);
            w = rl[7];
            acc = fmaf(w.x, lseB - v7.x, acc); acc = fmaf(w.y, lseB - v7.y, acc);
            acc = fmaf(w.z, lseB - v7.z, acc); acc = fmaf(w.w, lseB - v7.w, acc);
            w = rl[8];
            acc = fmaf(w.x, lseB - v8.x, acc); acc = fmaf(w.y, lseB - v8.y, acc);
            acc = fmaf(w.z, lseB - v8.z, acc); acc = fmaf(w.w, lseB - v8.w, acc);
        }
    }

    // generic tail (B % TROWS != 0) — empty for B = 2,000,000
    for (int row = nTiles * TROWS + blockIdx.x * blockDim.x + tid; row < B;
         row += gridDim.x * blockDim.x) {
        const float2* o2 = (const float2*)(logits + (size_t)row * NCLS);
        const float2* l2 = (const float2*)(labels + (size_t)row * NCLS);
        float x[NCLS], l[NCLS];
        #pragma unroll
        for (int k = 0; k < NCLS / 2; ++k) {
            float2 v = o2[k]; x[2 * k] = v.x; x[2 * k + 1] = v.y;
            float2 w = l2[k]; l[2 * k] = w.x; l[2 * k + 1] = w.y;
        }
        float mm = x[0];
        #pragma unroll
        for (int c = 1; c < NCLS; ++c) mm = fmaxf(mm, x[c]);
        float se = 0.f, dot = 0.f, sl = 0.f;
        #pragma unroll
        for (int c = 0; c < NCLS; ++c) {
            se += __expf(x[c] - mm);
            dot = fmaf(l[c], x[c], dot);
            sl += l[c];
        }
        acc = fmaf(sl, mm + __logf(se), acc - dot);
    }

    // block reduction -> plain store of partial (no atomic, no memset)
    #pragma unroll
    for (int off = 32; off > 0; off >>= 1)
        acc += __shfl_down(acc, off, 64);
    if (lane == 0) sWS[wid] = acc;
    __syncthreads();
    if (tid == 0)
        partial[blockIdx.x] = sWS[0] + sWS[1] + sWS[2] + sWS[3];
}

__global__ __launch_bounds__(256) void ce_soft_finish(
    const float* __restrict__ partial, float* __restrict__ result,
    int n, float invB)
{
    float s = 0.f;
    for (int i = threadIdx.x; i < n; i += 256) s += partial[i];
    #pragma unroll
    for (int off = 32; off > 0; off >>= 1)
        s += __shfl_down(s, off, 64);
    __shared__ float ws[4];
    int lane = threadIdx.x & 63, wid = threadIdx.x >> 6;
    if (lane == 0) ws[wid] = s;
    __syncthreads();
    if (threadIdx.x == 0)
        result[0] = (ws[0] + ws[1] + ws[2] + ws[3]) * invB;  // plain store overwrites poison
}

extern "C" void kernel_launch(void* const* d_in, const int* in_sizes, int n_in,
                              void* d_out, int out_size, void* d_ws, size_t ws_size,
                              hipStream_t stream) {
    const float* logits = (const float*)d_in[0];
    const float* labels = (const float*)d_in[1];
    float* result = (float*)d_out;

    int B = in_sizes[0] / NCLS;            // 2,000,000

    // grid = 512: 2 blocks/CU (LDS-capped, 73.7 KiB/block) x 256 CU = exactly resident
    int grid = 512;
    if (ws_size < (size_t)grid * sizeof(float)) {
        grid = (int)(ws_size / sizeof(float));
        if (grid > 512) grid = 512;
        if (grid < 1) grid = 1;
    }
    float* partial = (float*)d_ws;

    ce_soft_main<<<grid, 256, 0, stream>>>(logits, labels, partial, B);
    ce_soft_finish<<<1, 256, 0, stream>>>(partial, result, grid, 1.0f / (float)B);
}